// Round 1
// baseline (420.111 us; speedup 1.0000x reference)
//
#include <hip/hip_runtime.h>
#include <cmath>
#include <cfloat>

#define B_N 32
#define A_N 8400
#define G_N 32
#define C_N 80
#define NBLK_A 33            // ceil(8400/256)
#define NP (NBLK_A * B_N)    // 1056 partial blocks

// ---------- common device helpers ----------

__device__ __forceinline__ float pred_at(const float* __restrict__ p0,
                                         const float* __restrict__ p1,
                                         const float* __restrict__ p2,
                                         int b, int a, int c) {
  // flattened prediction out[b, a, c]; levels are (85,80,80),(85,40,40),(85,20,20)
  if (a < 6400)      return p0[(size_t)(b * 85 + c) * 6400 + a];
  else if (a < 8000) return p1[(size_t)(b * 85 + c) * 1600 + (a - 6400)];
  else               return p2[(size_t)(b * 85 + c) * 400  + (a - 8000)];
}

__device__ __forceinline__ void anchor_info(int a, float& cx, float& cy, float& st) {
  if (a < 6400)      { int h = a / 80;            int w = a - h * 80; cx = (w + 0.5f) * 8.f;  cy = (h + 0.5f) * 8.f;  st = 8.f;  }
  else if (a < 8000) { int t = a - 6400; int h = t / 40; int w = t - h * 40; cx = (w + 0.5f) * 16.f; cy = (h + 0.5f) * 16.f; st = 16.f; }
  else               { int t = a - 8000; int h = t / 20; int w = t - h * 20; cx = (w + 0.5f) * 32.f; cy = (h + 0.5f) * 32.f; st = 32.f; }
}

__device__ __forceinline__ float pair_iou(float gx, float gy, float gw, float gh,
                                          float px, float py, float pw, float ph) {
  float gx1 = gx - 0.5f * gw, gy1 = gy - 0.5f * gh, gx2 = gx + 0.5f * gw, gy2 = gy + 0.5f * gh;
  float px1 = px - 0.5f * pw, py1 = py - 0.5f * ph, px2 = px + 0.5f * pw, py2 = py + 0.5f * ph;
  float iw = fmaxf(fminf(gx2, px2) - fmaxf(gx1, px1), 0.f);
  float ih = fmaxf(fminf(gy2, py2) - fmaxf(gy1, py1), 0.f);
  float inter = iw * ih;
  return inter / (gw * gh + pw * ph - inter + 1e-16f);
}

__device__ __forceinline__ bool in_box_f(float cx, float cy, float gx, float gy, float gw, float gh) {
  float lx = gx - 0.5f * gw, ly = gy - 0.5f * gh, rx = gx + 0.5f * gw, ry = gy + 0.5f * gh;
  float m = fminf(fminf(cx - lx, cy - ly), fminf(rx - cx, ry - cy));
  return m > 0.f;
}

__device__ __forceinline__ bool in_ctr_f(float cx, float cy, float st, float gx, float gy) {
  float r = 2.5f * st;
  float m = fminf(fminf(cx - (gx - r), cy - (gy - r)), fminf((gx + r) - cx, (gy + r) - cy));
  return m > 0.f;
}

// ---------- kernel A: s0, fg_or, init asg/miou ----------

__global__ __launch_bounds__(256) void kA(const float* __restrict__ p0, const float* __restrict__ p1,
                                          const float* __restrict__ p2, const float* __restrict__ labels,
                                          float* __restrict__ s0, unsigned char* __restrict__ fgor,
                                          int* __restrict__ asg, float* __restrict__ miou) {
  int b = blockIdx.y;
  int a = blockIdx.x * 256 + threadIdx.x;
  __shared__ float lab[G_N * 5];
  if (threadIdx.x < G_N * 5) lab[threadIdx.x] = labels[b * G_N * 5 + threadIdx.x];
  __syncthreads();
  if (a >= A_N) return;

  float obj = pred_at(p0, p1, p2, b, a, 4);
  float s = 0.f;
  for (int c = 0; c < C_N; ++c) {
    float v = pred_at(p0, p1, p2, b, a, 5 + c);
    float p = sqrtf(v * obj);
    s += fmaxf(log1pf(-p), -100.f);
  }
  s0[b * A_N + a] = s;

  float cx, cy, st; anchor_info(a, cx, cy, st);
  bool any = false;
  for (int g = 0; g < G_N; ++g) {
    float gx = lab[g * 5 + 1], gy = lab[g * 5 + 2], gw = lab[g * 5 + 3], gh = lab[g * 5 + 4];
    any = any || in_box_f(cx, cy, gx, gy, gw, gh) || in_ctr_f(cx, cy, st, gx, gy);
  }
  fgor[b * A_N + a] = any ? 1 : 0;
  asg[b * A_N + a] = -1;
  miou[b * A_N + a] = 0.f;
}

// ---------- kernel B: per-(b,g) top-k selection ----------

#define LESSCI(c1, i1, c2, i2) (((c1) < (c2)) || ((c1) == (c2) && (i1) < (i2)))

__global__ __launch_bounds__(256) void kB(const float* __restrict__ p0, const float* __restrict__ p1,
                                          const float* __restrict__ p2, const float* __restrict__ labels,
                                          const float* __restrict__ s0, const unsigned char* __restrict__ fgor,
                                          int* __restrict__ match_idx, int* __restrict__ match_n) {
  int g = blockIdx.x, b = blockIdx.y, tid = threadIdx.x;
  __shared__ float slab[5];
  __shared__ float lds_c[256 * 10];
  __shared__ int   lds_i[256 * 10];
  __shared__ float lds_v[256 * 10];
  if (tid < 5) slab[tid] = labels[(b * G_N + g) * 5 + tid];
  __syncthreads();
  float gx = slab[1], gy = slab[2], gw = slab[3], gh = slab[4];
  int cid = (int)slab[0];

  float c10[10]; int i10[10]; float v10[10];
#pragma unroll
  for (int t = 0; t < 10; ++t) { c10[t] = INFINITY; i10[t] = 0x7fffffff; v10[t] = 0.f; }

  for (int a = tid; a < A_N; a += 256) {
    float cx, cy, st; anchor_info(a, cx, cy, st);
    float px = pred_at(p0, p1, p2, b, a, 0);
    float py = pred_at(p0, p1, p2, b, a, 1);
    float pw = pred_at(p0, p1, p2, b, a, 2);
    float ph = pred_at(p0, p1, p2, b, a, 3);
    float obj = pred_at(p0, p1, p2, b, a, 4);
    float iou = pair_iou(gx, gy, gw, gh, px, py, pw, ph);
    bool fg = fgor[b * A_N + a] != 0;

    // top-10 largest iou_m (value only)
    float iv = fg ? iou : 0.f;
    if (iv > v10[9]) {
      float nv = iv;
#pragma unroll
      for (int t = 0; t < 10; ++t) {
        if (nv > v10[t]) { float tf = v10[t]; v10[t] = nv; nv = tf; }
      }
    }

    // cost
    float clsv = pred_at(p0, p1, p2, b, a, 5 + cid);
    float p = sqrtf(clsv * obj);
    float l1 = fmaxf(logf(p), -100.f);
    float l0 = fmaxf(log1pf(-p), -100.f);
    float cst = (-l1 + l0 - s0[b * A_N + a]) - 3.f * logf(iou + 1e-8f);
    bool vb = in_box_f(cx, cy, gx, gy, gw, gh);
    bool vc = in_ctr_f(cx, cy, st, gx, gy);
    if (!(vb && vc)) cst += 100000.f;
    if (!fg) cst += 1e9f;

    if (LESSCI(cst, a, c10[9], i10[9])) {
      float nc = cst; int ni = a;
#pragma unroll
      for (int t = 0; t < 10; ++t) {
        bool lt = LESSCI(nc, ni, c10[t], i10[t]);
        if (lt) { float tf = c10[t]; c10[t] = nc; nc = tf; int ti = i10[t]; i10[t] = ni; ni = ti; }
      }
    }
  }

  // write lists to LDS and tree-merge
#pragma unroll
  for (int t = 0; t < 10; ++t) { lds_c[tid * 10 + t] = c10[t]; lds_i[tid * 10 + t] = i10[t]; lds_v[tid * 10 + t] = v10[t]; }
  __syncthreads();
  for (int s = 128; s >= 1; s >>= 1) {
    if (tid < s) {
      int ba = tid * 10, bb = (tid + s) * 10;
      float tc[10]; int ti[10]; float tv[10];
      int pa = 0, pb = 0;
#pragma unroll
      for (int t = 0; t < 10; ++t) {
        float ca = lds_c[ba + pa]; int ia = lds_i[ba + pa];
        float cb = lds_c[bb + pb]; int ib = lds_i[bb + pb];
        bool ta = LESSCI(ca, ia, cb, ib) || (ca == cb && ia == ib);
        tc[t] = ta ? ca : cb; ti[t] = ta ? ia : ib; pa += ta ? 1 : 0; pb += ta ? 0 : 1;
      }
      int qa = 0, qb = 0;
#pragma unroll
      for (int t = 0; t < 10; ++t) {
        float va = lds_v[ba + qa], vb2 = lds_v[bb + qb];
        bool ta = va >= vb2;
        tv[t] = ta ? va : vb2; qa += ta ? 1 : 0; qb += ta ? 0 : 1;
      }
#pragma unroll
      for (int t = 0; t < 10; ++t) { lds_c[ba + t] = tc[t]; lds_i[ba + t] = ti[t]; lds_v[ba + t] = tv[t]; }
    }
    __syncthreads();
  }

  if (tid == 0) {
    float s = 0.f;
#pragma unroll
    for (int t = 0; t < 10; ++t) s += lds_v[t];       // descending order, like jnp.sum(topk)
    int k = (int)s;
    if (k < 1) k = 1;
    if (k > 10) k = 10;
    match_n[b * G_N + g] = k;
    for (int t = 0; t < k; ++t) match_idx[(b * G_N + g) * 10 + t] = lds_i[t];
  }
}

// ---------- kernel C: dedup & final assignment ----------

__global__ __launch_bounds__(256) void kC(const float* __restrict__ p0, const float* __restrict__ p1,
                                          const float* __restrict__ p2, const float* __restrict__ labels,
                                          const float* __restrict__ s0, const unsigned char* __restrict__ fgor,
                                          const int* __restrict__ match_idx, const int* __restrict__ match_n,
                                          int* __restrict__ asg, float* __restrict__ miou) {
  int b = blockIdx.x, tid = threadIdx.x;
  __shared__ float lab[G_N * 5];
  __shared__ int ent_a[G_N * 10];
  if (tid < G_N * 5) lab[tid] = labels[b * G_N * 5 + tid];
  for (int e = tid; e < G_N * 10; e += 256) {
    int g = e / 10, t = e - g * 10;
    int n = match_n[b * G_N + g];
    ent_a[e] = (t < n) ? match_idx[(b * G_N + g) * 10 + t] : -1;
  }
  __syncthreads();

  for (int e = tid; e < G_N * 10; e += 256) {
    int a = ent_a[e];
    if (a < 0) continue;
    int g = e / 10;
    int cnt = 0;
    for (int e2 = 0; e2 < G_N * 10; ++e2) cnt += (ent_a[e2] == a) ? 1 : 0;

    float cx, cy, st; anchor_info(a, cx, cy, st);
    float px = pred_at(p0, p1, p2, b, a, 0);
    float py = pred_at(p0, p1, p2, b, a, 1);
    float pw = pred_at(p0, p1, p2, b, a, 2);
    float ph = pred_at(p0, p1, p2, b, a, 3);
    float obj = pred_at(p0, p1, p2, b, a, 4);

    int gf = g;
    if (cnt > 1) {
      // argmin over ALL gts of cost[:, a] (first index wins ties) — matches jnp.argmin
      float s0v = s0[b * A_N + a];
      bool fg = fgor[b * A_N + a] != 0;
      float best = INFINITY; gf = 0;
      for (int g2 = 0; g2 < G_N; ++g2) {
        float g2x = lab[g2 * 5 + 1], g2y = lab[g2 * 5 + 2], g2w = lab[g2 * 5 + 3], g2h = lab[g2 * 5 + 4];
        int cid = (int)lab[g2 * 5 + 0];
        float iou = pair_iou(g2x, g2y, g2w, g2h, px, py, pw, ph);
        float clsv = pred_at(p0, p1, p2, b, a, 5 + cid);
        float p = sqrtf(clsv * obj);
        float l1 = fmaxf(logf(p), -100.f);
        float l0 = fmaxf(log1pf(-p), -100.f);
        float cst = (-l1 + l0 - s0v) - 3.f * logf(iou + 1e-8f);
        bool vb = in_box_f(cx, cy, g2x, g2y, g2w, g2h);
        bool vc = in_ctr_f(cx, cy, st, g2x, g2y);
        if (!(vb && vc)) cst += 100000.f;
        if (!fg) cst += 1e9f;
        if (cst < best) { best = cst; gf = g2; }
      }
    }
    float gfx = lab[gf * 5 + 1], gfy = lab[gf * 5 + 2], gfw = lab[gf * 5 + 3], gfh = lab[gf * 5 + 4];
    float mi = pair_iou(gfx, gfy, gfw, gfh, px, py, pw, ph);
    asg[b * A_N + a] = gf;       // identical redundant writes when cnt>1 -> benign
    miou[b * A_N + a] = mi;
  }
}

// ---------- kernel D: per-anchor loss terms + block reduction ----------

__global__ __launch_bounds__(256) void kD(const float* __restrict__ p0, const float* __restrict__ p1,
                                          const float* __restrict__ p2, const float* __restrict__ labels,
                                          const int* __restrict__ asg, const float* __restrict__ miou,
                                          double* __restrict__ part, int* __restrict__ partn) {
  int b = blockIdx.y, tid = threadIdx.x;
  int a = blockIdx.x * 256 + tid;
  double so = 0.0, si = 0.0, sc = 0.0; int nf = 0;
  if (a < A_N) {
    float obj = pred_at(p0, p1, p2, b, a, 4);
    float l1 = fmaxf(logf(obj), -100.f);
    float l0 = fmaxf(log1pf(-obj), -100.f);
    int g = asg[b * A_N + a];
    if (g >= 0) {
      so = (double)(-l1);    // bce(obj, 1)
      nf = 1;
      float gx = labels[(b * G_N + g) * 5 + 1], gy = labels[(b * G_N + g) * 5 + 2];
      float gw = labels[(b * G_N + g) * 5 + 3], gh = labels[(b * G_N + g) * 5 + 4];
      float px = pred_at(p0, p1, p2, b, a, 0);
      float py = pred_at(p0, p1, p2, b, a, 1);
      float pw = pred_at(p0, p1, p2, b, a, 2);
      float ph = pred_at(p0, p1, p2, b, a, 3);
      float iou = pair_iou(gx, gy, gw, gh, px, py, pw, ph);
      float term = 1.f - iou * iou;
      si = (double)term;
      float mi = miou[b * A_N + a];
      int cid = (int)labels[(b * G_N + g) * 5 + 0];
      double accum = 0.0;
      for (int c = 0; c < C_N; ++c) {
        float pc = pred_at(p0, p1, p2, b, a, 5 + c);
        float cl1 = fmaxf(logf(pc), -100.f);
        float cl0 = fmaxf(log1pf(-pc), -100.f);
        float t = (c == cid) ? mi : 0.f;
        accum += (double)(-(t * cl1 + (1.f - t) * cl0));
      }
      sc = accum;
    } else {
      so = (double)(-l0);    // bce(obj, 0)
    }
  }
  __shared__ double ro[256], ri[256], rc[256];
  __shared__ int rn[256];
  ro[tid] = so; ri[tid] = si; rc[tid] = sc; rn[tid] = nf;
  __syncthreads();
  for (int s = 128; s >= 1; s >>= 1) {
    if (tid < s) { ro[tid] += ro[tid + s]; ri[tid] += ri[tid + s]; rc[tid] += rc[tid + s]; rn[tid] += rn[tid + s]; }
    __syncthreads();
  }
  if (tid == 0) {
    int pb = blockIdx.y * gridDim.x + blockIdx.x;
    part[pb * 3 + 0] = ro[0];
    part[pb * 3 + 1] = ri[0];
    part[pb * 3 + 2] = rc[0];
    partn[pb] = rn[0];
  }
}

// ---------- kernel E: final deterministic reduction ----------

__global__ __launch_bounds__(256) void kE(const double* __restrict__ part, const int* __restrict__ partn,
                                          float* __restrict__ out, int nP) {
  int tid = threadIdx.x;
  double o = 0.0, i = 0.0, c = 0.0; int n = 0;
  for (int p = tid; p < nP; p += 256) {
    o += part[p * 3 + 0]; i += part[p * 3 + 1]; c += part[p * 3 + 2]; n += partn[p];
  }
  __shared__ double ro[256], ri[256], rc[256];
  __shared__ int rn[256];
  ro[tid] = o; ri[tid] = i; rc[tid] = c; rn[tid] = n;
  __syncthreads();
  for (int s = 128; s >= 1; s >>= 1) {
    if (tid < s) { ro[tid] += ro[tid + s]; ri[tid] += ri[tid + s]; rc[tid] += rc[tid + s]; rn[tid] += rn[tid + s]; }
    __syncthreads();
  }
  if (tid == 0) {
    float gt = fmaxf((float)rn[0], 1.f);
    float li = (float)((5.0 * ri[0]) / (double)gt);
    float lo = (float)(ro[0] / (double)gt);
    float lc = (float)(rc[0] / (double)gt);
    out[0] = li + lo + lc;
    out[1] = li;
    out[2] = lo;
    out[3] = lc;
    out[4] = gt;
  }
}

// ---------- launch ----------

extern "C" void kernel_launch(void* const* d_in, const int* in_sizes, int n_in,
                              void* d_out, int out_size, void* d_ws, size_t ws_size,
                              hipStream_t stream) {
  const float* p0 = (const float*)d_in[0];
  const float* p1 = (const float*)d_in[1];
  const float* p2 = (const float*)d_in[2];
  const float* labels = (const float*)d_in[3];
  float* out = (float*)d_out;

  char* w = (char*)d_ws;
  auto alloc = [&](size_t bytes) -> void* {
    void* p = (void*)w;
    w += (bytes + 255) & ~(size_t)255;
    return p;
  };
  double* part = (double*)alloc((size_t)NP * 3 * sizeof(double));
  float* s0 = (float*)alloc((size_t)B_N * A_N * sizeof(float));
  float* miou = (float*)alloc((size_t)B_N * A_N * sizeof(float));
  int* asg = (int*)alloc((size_t)B_N * A_N * sizeof(int));
  int* match_idx = (int*)alloc((size_t)B_N * G_N * 10 * sizeof(int));
  int* match_n = (int*)alloc((size_t)B_N * G_N * sizeof(int));
  int* partn = (int*)alloc((size_t)NP * sizeof(int));
  unsigned char* fgor = (unsigned char*)alloc((size_t)B_N * A_N);

  dim3 gA(NBLK_A, B_N);
  kA<<<gA, 256, 0, stream>>>(p0, p1, p2, labels, s0, fgor, asg, miou);
  dim3 gB(G_N, B_N);
  kB<<<gB, 256, 0, stream>>>(p0, p1, p2, labels, s0, fgor, match_idx, match_n);
  kC<<<B_N, 256, 0, stream>>>(p0, p1, p2, labels, s0, fgor, match_idx, match_n, asg, miou);
  dim3 gD(NBLK_A, B_N);
  kD<<<gD, 256, 0, stream>>>(p0, p1, p2, labels, asg, miou, part, partn);
  kE<<<1, 256, 0, stream>>>(part, partn, out, NP);
}

// Round 2
// 194.847 us; speedup vs baseline: 2.1561x; 2.1561x over previous
//
#include <hip/hip_runtime.h>
#include <cmath>
#include <cfloat>

#define B_N 32
#define A_N 8400
#define G_N 32
#define C_N 80
#define NBLK_A 33            // ceil(8400/256)
#define NP (NBLK_A * B_N)    // 1056 partial blocks

// ---------- common device helpers ----------

// fast log: v_log_f32 (native log2) * ln2. x=0 -> -inf -> later fmax(-100) clamps.
__device__ __forceinline__ float flog(float x) {
  return __log2f(x) * 0.6931471805599453f;
}

__device__ __forceinline__ float pred_at(const float* __restrict__ p0,
                                         const float* __restrict__ p1,
                                         const float* __restrict__ p2,
                                         int b, int a, int c) {
  // flattened prediction out[b, a, c]; levels are (85,80,80),(85,40,40),(85,20,20)
  if (a < 6400)      return p0[(size_t)(b * 85 + c) * 6400 + a];
  else if (a < 8000) return p1[(size_t)(b * 85 + c) * 1600 + (a - 6400)];
  else               return p2[(size_t)(b * 85 + c) * 400  + (a - 8000)];
}

__device__ __forceinline__ void anchor_info(int a, float& cx, float& cy, float& st) {
  if (a < 6400)      { int h = a / 80;            int w = a - h * 80; cx = (w + 0.5f) * 8.f;  cy = (h + 0.5f) * 8.f;  st = 8.f;  }
  else if (a < 8000) { int t = a - 6400; int h = t / 40; int w = t - h * 40; cx = (w + 0.5f) * 16.f; cy = (h + 0.5f) * 16.f; st = 16.f; }
  else               { int t = a - 8000; int h = t / 20; int w = t - h * 20; cx = (w + 0.5f) * 32.f; cy = (h + 0.5f) * 32.f; st = 32.f; }
}

__device__ __forceinline__ float pair_iou(float gx, float gy, float gw, float gh,
                                          float px, float py, float pw, float ph) {
  float gx1 = gx - 0.5f * gw, gy1 = gy - 0.5f * gh, gx2 = gx + 0.5f * gw, gy2 = gy + 0.5f * gh;
  float px1 = px - 0.5f * pw, py1 = py - 0.5f * ph, px2 = px + 0.5f * pw, py2 = py + 0.5f * ph;
  float iw = fmaxf(fminf(gx2, px2) - fmaxf(gx1, px1), 0.f);
  float ih = fmaxf(fminf(gy2, py2) - fmaxf(gy1, py1), 0.f);
  float inter = iw * ih;
  return inter / (gw * gh + pw * ph - inter + 1e-16f);
}

__device__ __forceinline__ bool in_box_f(float cx, float cy, float gx, float gy, float gw, float gh) {
  float lx = gx - 0.5f * gw, ly = gy - 0.5f * gh, rx = gx + 0.5f * gw, ry = gy + 0.5f * gh;
  float m = fminf(fminf(cx - lx, cy - ly), fminf(rx - cx, ry - cy));
  return m > 0.f;
}

__device__ __forceinline__ bool in_ctr_f(float cx, float cy, float st, float gx, float gy) {
  float r = 2.5f * st;
  float m = fminf(fminf(cx - (gx - r), cy - (gy - r)), fminf((gx + r) - cx, (gy + r) - cy));
  return m > 0.f;
}

// ---------- kernel A: s0 (sqrt-BCE sum), s1 (raw cls log(1-p) sum), fg_or, init asg ----------

__global__ __launch_bounds__(256) void kA(const float* __restrict__ p0, const float* __restrict__ p1,
                                          const float* __restrict__ p2, const float* __restrict__ labels,
                                          float* __restrict__ s0, float* __restrict__ s1,
                                          unsigned char* __restrict__ fgor,
                                          int* __restrict__ asg, float* __restrict__ miou) {
  int b = blockIdx.y;
  int a = blockIdx.x * 256 + threadIdx.x;
  __shared__ float lab[G_N * 5];
  if (threadIdx.x < G_N * 5) lab[threadIdx.x] = labels[b * G_N * 5 + threadIdx.x];
  __syncthreads();
  if (a >= A_N) return;

  float obj = pred_at(p0, p1, p2, b, a, 4);
  float s_sqrt = 0.f;   // sum_c clip(log(1 - sqrt(cls_c*obj)), -100)
  float s_raw  = 0.f;   // sum_c clip(log(1 - cls_c), -100)
  for (int c = 0; c < C_N; ++c) {
    float v = pred_at(p0, p1, p2, b, a, 5 + c);
    float p = sqrtf(v * obj);
    s_sqrt += fmaxf(flog(1.f - p), -100.f);
    s_raw  += fmaxf(flog(1.f - v), -100.f);
  }
  s0[b * A_N + a] = s_sqrt;
  s1[b * A_N + a] = s_raw;

  float cx, cy, st; anchor_info(a, cx, cy, st);
  bool any = false;
  for (int g = 0; g < G_N; ++g) {
    float gx = lab[g * 5 + 1], gy = lab[g * 5 + 2], gw = lab[g * 5 + 3], gh = lab[g * 5 + 4];
    any = any || in_box_f(cx, cy, gx, gy, gw, gh) || in_ctr_f(cx, cy, st, gx, gy);
  }
  fgor[b * A_N + a] = any ? 1 : 0;
  asg[b * A_N + a] = -1;
  miou[b * A_N + a] = 0.f;
}

// ---------- kernel B: per-(b,g) top-k selection ----------

#define LESSCI(c1, i1, c2, i2) (((c1) < (c2)) || ((c1) == (c2) && (i1) < (i2)))

__global__ __launch_bounds__(256) void kB(const float* __restrict__ p0, const float* __restrict__ p1,
                                          const float* __restrict__ p2, const float* __restrict__ labels,
                                          const float* __restrict__ s0, const unsigned char* __restrict__ fgor,
                                          int* __restrict__ match_idx, int* __restrict__ match_n) {
  int g = blockIdx.x, b = blockIdx.y, tid = threadIdx.x;
  __shared__ float slab[5];
  // [slot][thread] layout: bank = tid%32 for any slot -> conflict-free merge
  __shared__ float lds_c[10 * 256];
  __shared__ int   lds_i[10 * 256];
  __shared__ float lds_v[10 * 256];
  if (tid < 5) slab[tid] = labels[(b * G_N + g) * 5 + tid];
  __syncthreads();
  float gx = slab[1], gy = slab[2], gw = slab[3], gh = slab[4];
  int cid = (int)slab[0];

  float c10[10]; int i10[10]; float v10[10];
#pragma unroll
  for (int t = 0; t < 10; ++t) { c10[t] = INFINITY; i10[t] = 0x7fffffff; v10[t] = 0.f; }

  for (int a = tid; a < A_N; a += 256) {
    float cx, cy, st; anchor_info(a, cx, cy, st);
    float px = pred_at(p0, p1, p2, b, a, 0);
    float py = pred_at(p0, p1, p2, b, a, 1);
    float pw = pred_at(p0, p1, p2, b, a, 2);
    float ph = pred_at(p0, p1, p2, b, a, 3);
    float obj = pred_at(p0, p1, p2, b, a, 4);
    float iou = pair_iou(gx, gy, gw, gh, px, py, pw, ph);
    bool fg = fgor[b * A_N + a] != 0;

    // top-10 largest iou_m (value only)
    float iv = fg ? iou : 0.f;
    if (iv > v10[9]) {
      float nv = iv;
#pragma unroll
      for (int t = 0; t < 10; ++t) {
        if (nv > v10[t]) { float tf = v10[t]; v10[t] = nv; nv = tf; }
      }
    }

    // cost (fast logs)
    float clsv = pred_at(p0, p1, p2, b, a, 5 + cid);
    float p = sqrtf(clsv * obj);
    float l1 = fmaxf(flog(p), -100.f);
    float l0 = fmaxf(flog(1.f - p), -100.f);
    float cst = (-l1 + l0 - s0[b * A_N + a]) - 3.f * flog(iou + 1e-8f);
    bool vb = in_box_f(cx, cy, gx, gy, gw, gh);
    bool vc = in_ctr_f(cx, cy, st, gx, gy);
    if (!(vb && vc)) cst += 100000.f;
    if (!fg) cst += 1e9f;

    if (LESSCI(cst, a, c10[9], i10[9])) {
      float nc = cst; int ni = a;
#pragma unroll
      for (int t = 0; t < 10; ++t) {
        bool lt = LESSCI(nc, ni, c10[t], i10[t]);
        if (lt) { float tf = c10[t]; c10[t] = nc; nc = tf; int ti = i10[t]; i10[t] = ni; ni = ti; }
      }
    }
  }

  // write lists to LDS ([slot][thread]) and tree-merge
#pragma unroll
  for (int t = 0; t < 10; ++t) { lds_c[t * 256 + tid] = c10[t]; lds_i[t * 256 + tid] = i10[t]; lds_v[t * 256 + tid] = v10[t]; }
  __syncthreads();
  for (int s = 128; s >= 1; s >>= 1) {
    if (tid < s) {
      int ca = tid, cb = tid + s;
      float tc[10]; int ti[10]; float tv[10];
      int pa = 0, pb = 0;
#pragma unroll
      for (int t = 0; t < 10; ++t) {
        float va = lds_c[pa * 256 + ca]; int ia = lds_i[pa * 256 + ca];
        float vb = lds_c[pb * 256 + cb]; int ib = lds_i[pb * 256 + cb];
        bool ta = LESSCI(va, ia, vb, ib) || (va == vb && ia == ib);
        tc[t] = ta ? va : vb; ti[t] = ta ? ia : ib; pa += ta ? 1 : 0; pb += ta ? 0 : 1;
      }
      int qa = 0, qb = 0;
#pragma unroll
      for (int t = 0; t < 10; ++t) {
        float va = lds_v[qa * 256 + ca], vb2 = lds_v[qb * 256 + cb];
        bool ta = va >= vb2;
        tv[t] = ta ? va : vb2; qa += ta ? 1 : 0; qb += ta ? 0 : 1;
      }
#pragma unroll
      for (int t = 0; t < 10; ++t) { lds_c[t * 256 + ca] = tc[t]; lds_i[t * 256 + ca] = ti[t]; lds_v[t * 256 + ca] = tv[t]; }
    }
    __syncthreads();
  }

  if (tid == 0) {
    float s = 0.f;
#pragma unroll
    for (int t = 0; t < 10; ++t) s += lds_v[t * 256];   // descending order, like jnp.sum(top_k)
    int k = (int)s;
    if (k < 1) k = 1;
    if (k > 10) k = 10;
    match_n[b * G_N + g] = k;
    for (int t = 0; t < k; ++t) match_idx[(b * G_N + g) * 10 + t] = lds_i[t * 256];
  }
}

// ---------- kernel C: dedup & final assignment ----------

__global__ __launch_bounds__(256) void kC(const float* __restrict__ p0, const float* __restrict__ p1,
                                          const float* __restrict__ p2, const float* __restrict__ labels,
                                          const float* __restrict__ s0, const unsigned char* __restrict__ fgor,
                                          const int* __restrict__ match_idx, const int* __restrict__ match_n,
                                          int* __restrict__ asg, float* __restrict__ miou) {
  int b = blockIdx.x, tid = threadIdx.x;
  __shared__ float lab[G_N * 5];
  __shared__ int ent_a[G_N * 10];
  if (tid < G_N * 5) lab[tid] = labels[b * G_N * 5 + tid];
  for (int e = tid; e < G_N * 10; e += 256) {
    int g = e / 10, t = e - g * 10;
    int n = match_n[b * G_N + g];
    ent_a[e] = (t < n) ? match_idx[(b * G_N + g) * 10 + t] : -1;
  }
  __syncthreads();

  for (int e = tid; e < G_N * 10; e += 256) {
    int a = ent_a[e];
    if (a < 0) continue;
    int g = e / 10;
    int cnt = 0;
    for (int e2 = 0; e2 < G_N * 10; ++e2) cnt += (ent_a[e2] == a) ? 1 : 0;

    float cx, cy, st; anchor_info(a, cx, cy, st);
    float px = pred_at(p0, p1, p2, b, a, 0);
    float py = pred_at(p0, p1, p2, b, a, 1);
    float pw = pred_at(p0, p1, p2, b, a, 2);
    float ph = pred_at(p0, p1, p2, b, a, 3);
    float obj = pred_at(p0, p1, p2, b, a, 4);

    int gf = g;
    if (cnt > 1) {
      // argmin over ALL gts of cost[:, a] (first index wins ties)
      float s0v = s0[b * A_N + a];
      bool fg = fgor[b * A_N + a] != 0;
      float best = INFINITY; gf = 0;
      for (int g2 = 0; g2 < G_N; ++g2) {
        float g2x = lab[g2 * 5 + 1], g2y = lab[g2 * 5 + 2], g2w = lab[g2 * 5 + 3], g2h = lab[g2 * 5 + 4];
        int cid = (int)lab[g2 * 5 + 0];
        float iou = pair_iou(g2x, g2y, g2w, g2h, px, py, pw, ph);
        float clsv = pred_at(p0, p1, p2, b, a, 5 + cid);
        float p = sqrtf(clsv * obj);
        float l1 = fmaxf(flog(p), -100.f);
        float l0 = fmaxf(flog(1.f - p), -100.f);
        float cst = (-l1 + l0 - s0v) - 3.f * flog(iou + 1e-8f);
        bool vb = in_box_f(cx, cy, g2x, g2y, g2w, g2h);
        bool vc = in_ctr_f(cx, cy, st, g2x, g2y);
        if (!(vb && vc)) cst += 100000.f;
        if (!fg) cst += 1e9f;
        if (cst < best) { best = cst; gf = g2; }
      }
    }
    float gfx = lab[gf * 5 + 1], gfy = lab[gf * 5 + 2], gfw = lab[gf * 5 + 3], gfh = lab[gf * 5 + 4];
    float mi = pair_iou(gfx, gfy, gfw, gfh, px, py, pw, ph);
    asg[b * A_N + a] = gf;       // identical redundant writes when cnt>1 -> benign
    miou[b * A_N + a] = mi;
  }
}

// ---------- kernel D: per-anchor loss terms (O(1) per anchor) + block reduction ----------

__global__ __launch_bounds__(256) void kD(const float* __restrict__ p0, const float* __restrict__ p1,
                                          const float* __restrict__ p2, const float* __restrict__ labels,
                                          const int* __restrict__ asg, const float* __restrict__ miou,
                                          const float* __restrict__ s1,
                                          double* __restrict__ part, int* __restrict__ partn) {
  int b = blockIdx.y, tid = threadIdx.x;
  int a = blockIdx.x * 256 + tid;
  double so = 0.0, si = 0.0, sc = 0.0; int nf = 0;
  if (a < A_N) {
    float obj = pred_at(p0, p1, p2, b, a, 4);
    int g = asg[b * A_N + a];
    if (g >= 0) {
      so = (double)(-fmaxf(flog(obj), -100.f));         // bce(obj, 1)
      nf = 1;
      float gx = labels[(b * G_N + g) * 5 + 1], gy = labels[(b * G_N + g) * 5 + 2];
      float gw = labels[(b * G_N + g) * 5 + 3], gh = labels[(b * G_N + g) * 5 + 4];
      float px = pred_at(p0, p1, p2, b, a, 0);
      float py = pred_at(p0, p1, p2, b, a, 1);
      float pw = pred_at(p0, p1, p2, b, a, 2);
      float ph = pred_at(p0, p1, p2, b, a, 3);
      float iou = pair_iou(gx, gy, gw, gh, px, py, pw, ph);
      si = (double)(1.f - iou * iou);
      // cls loss: sum_c bce = -s1 - t*l1_cid + t*l0_cid, t = miou
      float mi = miou[b * A_N + a];
      int cid = (int)labels[(b * G_N + g) * 5 + 0];
      float pc = pred_at(p0, p1, p2, b, a, 5 + cid);
      float l1c = fmaxf(flog(pc), -100.f);
      float l0c = fmaxf(flog(1.f - pc), -100.f);
      sc = (double)(-s1[b * A_N + a] - mi * l1c + mi * l0c);
    } else {
      so = (double)(-fmaxf(flog(1.f - obj), -100.f));   // bce(obj, 0)
    }
  }
  __shared__ double ro[256], ri[256], rc[256];
  __shared__ int rn[256];
  ro[tid] = so; ri[tid] = si; rc[tid] = sc; rn[tid] = nf;
  __syncthreads();
  for (int s = 128; s >= 1; s >>= 1) {
    if (tid < s) { ro[tid] += ro[tid + s]; ri[tid] += ri[tid + s]; rc[tid] += rc[tid + s]; rn[tid] += rn[tid + s]; }
    __syncthreads();
  }
  if (tid == 0) {
    int pb = blockIdx.y * gridDim.x + blockIdx.x;
    part[pb * 3 + 0] = ro[0];
    part[pb * 3 + 1] = ri[0];
    part[pb * 3 + 2] = rc[0];
    partn[pb] = rn[0];
  }
}

// ---------- kernel E: final deterministic reduction ----------

__global__ __launch_bounds__(256) void kE(const double* __restrict__ part, const int* __restrict__ partn,
                                          float* __restrict__ out, int nP) {
  int tid = threadIdx.x;
  double o = 0.0, i = 0.0, c = 0.0; int n = 0;
  for (int p = tid; p < nP; p += 256) {
    o += part[p * 3 + 0]; i += part[p * 3 + 1]; c += part[p * 3 + 2]; n += partn[p];
  }
  __shared__ double ro[256], ri[256], rc[256];
  __shared__ int rn[256];
  ro[tid] = o; ri[tid] = i; rc[tid] = c; rn[tid] = n;
  __syncthreads();
  for (int s = 128; s >= 1; s >>= 1) {
    if (tid < s) { ro[tid] += ro[tid + s]; ri[tid] += ri[tid + s]; rc[tid] += rc[tid + s]; rn[tid] += rn[tid + s]; }
    __syncthreads();
  }
  if (tid == 0) {
    float gt = fmaxf((float)rn[0], 1.f);
    float li = (float)((5.0 * ri[0]) / (double)gt);
    float lo = (float)(ro[0] / (double)gt);
    float lc = (float)(rc[0] / (double)gt);
    out[0] = li + lo + lc;
    out[1] = li;
    out[2] = lo;
    out[3] = lc;
    out[4] = gt;
  }
}

// ---------- launch ----------

extern "C" void kernel_launch(void* const* d_in, const int* in_sizes, int n_in,
                              void* d_out, int out_size, void* d_ws, size_t ws_size,
                              hipStream_t stream) {
  const float* p0 = (const float*)d_in[0];
  const float* p1 = (const float*)d_in[1];
  const float* p2 = (const float*)d_in[2];
  const float* labels = (const float*)d_in[3];
  float* out = (float*)d_out;

  char* w = (char*)d_ws;
  auto alloc = [&](size_t bytes) -> void* {
    void* p = (void*)w;
    w += (bytes + 255) & ~(size_t)255;
    return p;
  };
  double* part = (double*)alloc((size_t)NP * 3 * sizeof(double));
  float* s0 = (float*)alloc((size_t)B_N * A_N * sizeof(float));
  float* s1 = (float*)alloc((size_t)B_N * A_N * sizeof(float));
  float* miou = (float*)alloc((size_t)B_N * A_N * sizeof(float));
  int* asg = (int*)alloc((size_t)B_N * A_N * sizeof(int));
  int* match_idx = (int*)alloc((size_t)B_N * G_N * 10 * sizeof(int));
  int* match_n = (int*)alloc((size_t)B_N * G_N * sizeof(int));
  int* partn = (int*)alloc((size_t)NP * sizeof(int));
  unsigned char* fgor = (unsigned char*)alloc((size_t)B_N * A_N);

  dim3 gA(NBLK_A, B_N);
  kA<<<gA, 256, 0, stream>>>(p0, p1, p2, labels, s0, s1, fgor, asg, miou);
  dim3 gB(G_N, B_N);
  kB<<<gB, 256, 0, stream>>>(p0, p1, p2, labels, s0, fgor, match_idx, match_n);
  kC<<<B_N, 256, 0, stream>>>(p0, p1, p2, labels, s0, fgor, match_idx, match_n, asg, miou);
  dim3 gD(NBLK_A, B_N);
  kD<<<gD, 256, 0, stream>>>(p0, p1, p2, labels, asg, miou, s1, part, partn);
  kE<<<1, 256, 0, stream>>>(part, partn, out, NP);
}

// Round 3
// 115.218 us; speedup vs baseline: 3.6462x; 1.6911x over previous
//
#include <hip/hip_runtime.h>
#include <cmath>
#include <cfloat>

#define B_N 32
#define A_N 8400
#define G_N 32
#define C_N 80
#define NBLK_A 33            // ceil(8400/256)
#define NP (NBLK_A * B_N)

// ---------- common device helpers ----------

__device__ __forceinline__ float flog(float x) {
  return __log2f(x) * 0.6931471805599453f;
}

// channel base pointer + stride for anchor a (hoists the level branch)
__device__ __forceinline__ const float* chan_base(const float* __restrict__ p0,
                                                  const float* __restrict__ p1,
                                                  const float* __restrict__ p2,
                                                  int b, int a, int& cs) {
  if (a < 6400)      { cs = 6400; return p0 + (size_t)b * 85 * 6400 + a; }
  else if (a < 8000) { cs = 1600; return p1 + (size_t)b * 85 * 1600 + (a - 6400); }
  else               { cs = 400;  return p2 + (size_t)b * 85 * 400  + (a - 8000); }
}

__device__ __forceinline__ void anchor_info(int a, float& cx, float& cy, float& st) {
  if (a < 6400)      { int h = a / 80;            int w = a - h * 80; cx = (w + 0.5f) * 8.f;  cy = (h + 0.5f) * 8.f;  st = 8.f;  }
  else if (a < 8000) { int t = a - 6400; int h = t / 40; int w = t - h * 40; cx = (w + 0.5f) * 16.f; cy = (h + 0.5f) * 16.f; st = 16.f; }
  else               { int t = a - 8000; int h = t / 20; int w = t - h * 20; cx = (w + 0.5f) * 32.f; cy = (h + 0.5f) * 32.f; st = 32.f; }
}

__device__ __forceinline__ float pair_iou(float gx, float gy, float gw, float gh,
                                          float px, float py, float pw, float ph) {
  float gx1 = gx - 0.5f * gw, gy1 = gy - 0.5f * gh, gx2 = gx + 0.5f * gw, gy2 = gy + 0.5f * gh;
  float px1 = px - 0.5f * pw, py1 = py - 0.5f * ph, px2 = px + 0.5f * pw, py2 = py + 0.5f * ph;
  float iw = fmaxf(fminf(gx2, px2) - fmaxf(gx1, px1), 0.f);
  float ih = fmaxf(fminf(gy2, py2) - fmaxf(gy1, py1), 0.f);
  float inter = iw * ih;
  return inter / (gw * gh + pw * ph - inter + 1e-16f);
}

// ---------- kernel Z: zero fg counters ----------

__global__ void kZ(int* __restrict__ F_cnt) {
  if (threadIdx.x < B_N) F_cnt[threadIdx.x] = 0;
}

// ---------- kernel A: s0/s1, fg_or, asg init, fg-box compaction ----------

__global__ __launch_bounds__(256) void kA(const float* __restrict__ p0, const float* __restrict__ p1,
                                          const float* __restrict__ p2, const float* __restrict__ labels,
                                          float* __restrict__ s0, float* __restrict__ s1,
                                          unsigned char* __restrict__ fgor,
                                          int* __restrict__ asg,
                                          float4* __restrict__ F_box, int* __restrict__ F_cnt) {
  int b = blockIdx.y, tid = threadIdx.x;
  int a = blockIdx.x * 256 + tid;
  __shared__ float4 labf[G_N];          // (gx, gy, 0.5*gw, 0.5*gh)
  __shared__ float4 stage[256];
  __shared__ int s_cnt, s_base;
  if (tid < G_N) {
    const float* L = labels + (size_t)(b * G_N + tid) * 5;
    labf[tid] = make_float4(L[1], L[2], 0.5f * L[3], 0.5f * L[4]);
  }
  if (tid == 0) s_cnt = 0;
  __syncthreads();

  bool active = (a < A_N);
  bool fg = false;
  const float* pp = nullptr; int cs = 0;
  if (active) {
    pp = chan_base(p0, p1, p2, b, a, cs);
    float obj = pp[4 * cs];
    float l2s = 0.f, l2r = 0.f;
    for (int c = 0; c < C_N; c += 4) {
      float v0 = pp[(5 + c) * cs], v1 = pp[(6 + c) * cs], v2 = pp[(7 + c) * cs], v3 = pp[(8 + c) * cs];
      float q0 = 1.f - sqrtf(v0 * obj), q1 = 1.f - sqrtf(v1 * obj);
      float q2 = 1.f - sqrtf(v2 * obj), q3 = 1.f - sqrtf(v3 * obj);
      float r0 = 1.f - v0, r1 = 1.f - v1, r2 = 1.f - v2, r3 = 1.f - v3;
      l2s += __log2f(fmaxf((q0 * q1) * (q2 * q3), 1e-37f));
      l2r += __log2f(fmaxf((r0 * r1) * (r2 * r3), 1e-37f));
    }
    s0[b * A_N + a] = l2s * 0.6931471805599453f;
    s1[b * A_N + a] = l2r * 0.6931471805599453f;

    float cx, cy, st; anchor_info(a, cx, cy, st);
    float rr = 2.5f * st;
    for (int g = 0; g < G_N; ++g) {
      float4 L = labf[g];
      float dx = fabsf(cx - L.x), dy = fabsf(cy - L.y);
      fg = fg | ((dx < L.z) & (dy < L.w)) | ((dx < rr) & (dy < rr));
    }
    fgor[b * A_N + a] = fg ? 1 : 0;
    asg[b * A_N + a] = -1;
  }
  if (active && fg) {
    int pos = atomicAdd(&s_cnt, 1);
    stage[pos] = make_float4(pp[0], pp[cs], pp[2 * cs], pp[3 * cs]);
  }
  __syncthreads();
  if (tid == 0) s_base = atomicAdd(&F_cnt[b], s_cnt);
  __syncthreads();
  for (int i = tid; i < s_cnt; i += 256)
    F_box[(size_t)b * A_N + s_base + i] = stage[i];
}

// ---------- kernel B: per-(b,g) dyn_k + top-k selection ----------

#define LESSCI(c1, i1, c2, i2) (((c1) < (c2)) || ((c1) == (c2) && (i1) < (i2)))

__global__ __launch_bounds__(256) void kB(const float* __restrict__ p0, const float* __restrict__ p1,
                                          const float* __restrict__ p2, const float* __restrict__ labels,
                                          const float* __restrict__ s0, const unsigned char* __restrict__ fgor,
                                          const float4* __restrict__ F_box, const int* __restrict__ F_cnt,
                                          int* __restrict__ match_idx, int* __restrict__ match_n) {
  int g = blockIdx.x, b = blockIdx.y, tid = threadIdx.x;
  __shared__ float lds_c[10 * 256];
  __shared__ int   lds_i[10 * 256];
  __shared__ float slab[5];
  __shared__ int s_nV, s_dynk;
  if (tid < 5) slab[tid] = labels[(b * G_N + g) * 5 + tid];
  if (tid == 0) s_nV = 0;
  __syncthreads();
  float gx = slab[1], gy = slab[2], gw = slab[3], gh = slab[4];
  int cid = (int)slab[0];

  // ---- phase A: top-10 iou VALUES over compacted fg boxes (order-independent) ----
  float v10[10];
#pragma unroll
  for (int t = 0; t < 10; ++t) v10[t] = 0.f;
  int nF = F_cnt[b];
  const float4* bx = F_box + (size_t)b * A_N;
  for (int i = tid; i < nF; i += 256) {
    float4 B = bx[i];
    float iou = pair_iou(gx, gy, gw, gh, B.x, B.y, B.z, B.w);
    if (iou > v10[9]) {
      float nv = iou;
#pragma unroll
      for (int t = 0; t < 10; ++t)
        if (nv > v10[t]) { float tf = v10[t]; v10[t] = nv; nv = tf; }
    }
  }
#pragma unroll
  for (int t = 0; t < 10; ++t) lds_c[t * 256 + tid] = v10[t];
  __syncthreads();
  for (int s = 128; s >= 1; s >>= 1) {
    if (tid < s) {
      int ca = tid, cb = tid + s;
      float tv[10]; int qa = 0, qb = 0;
#pragma unroll
      for (int t = 0; t < 10; ++t) {
        float va = lds_c[qa * 256 + ca], vb = lds_c[qb * 256 + cb];
        bool ta = va >= vb;
        tv[t] = ta ? va : vb; qa += ta ? 1 : 0; qb += ta ? 0 : 1;
      }
#pragma unroll
      for (int t = 0; t < 10; ++t) lds_c[t * 256 + ca] = tv[t];
    }
    __syncthreads();
  }
  if (tid == 0) {
    float sum = 0.f;
#pragma unroll
    for (int t = 0; t < 10; ++t) sum += lds_c[t * 256];
    int k = (int)sum; if (k < 1) k = 1; if (k > 10) k = 10;
    s_dynk = k;
  }
  __syncthreads();
  int dynk = s_dynk;

  // ---- phase B: geometric valid candidates (<=147), exact cost, no penalties ----
  float cc = INFINITY; int ci = 0x7fffffff;
  if (tid < 147) {
    int lvl = tid / 49, r2 = tid % 49;
    int dh = r2 / 7 - 3, dw = r2 % 7 - 3;
    float st = (lvl == 0) ? 8.f : (lvl == 1) ? 16.f : 32.f;
    int Wg = (lvl == 0) ? 80 : (lvl == 1) ? 40 : 20;
    int basea = (lvl == 0) ? 0 : (lvl == 1) ? 6400 : 8000;
    int hc = (int)floorf(gy / st) + dh, wc = (int)floorf(gx / st) + dw;
    if (hc >= 0 && hc < Wg && wc >= 0 && wc < Wg) {
      int a = basea + hc * Wg + wc;
      float cx = (wc + 0.5f) * st, cy = (hc + 0.5f) * st;
      float dx = fabsf(cx - gx), dy = fabsf(cy - gy);
      bool ic = (dx < 2.5f * st) & (dy < 2.5f * st);
      bool ib = (dx < 0.5f * gw) & (dy < 0.5f * gh);
      if (ic && ib) {
        atomicAdd(&s_nV, 1);
        int cs; const float* pp = chan_base(p0, p1, p2, b, a, cs);
        float px = pp[0], py = pp[cs], pw = pp[2 * cs], ph = pp[3 * cs], obj = pp[4 * cs];
        float clsv = pp[(5 + cid) * cs];
        float iou = pair_iou(gx, gy, gw, gh, px, py, pw, ph);
        float p = sqrtf(clsv * obj);
        float l1 = fmaxf(flog(p), -100.f), l0 = fmaxf(flog(1.f - p), -100.f);
        cc = (-l1 + l0 - s0[b * A_N + a]) - 3.f * flog(iou + 1e-8f);
        ci = a;
      }
    }
  }
  lds_c[tid] = cc; lds_i[tid] = ci;
#pragma unroll
  for (int t = 1; t < 10; ++t) { lds_c[t * 256 + tid] = INFINITY; lds_i[t * 256 + tid] = 0x7fffffff; }
  __syncthreads();
  int nV = s_nV;
  for (int s = 128; s >= 1; s >>= 1) {
    if (tid < s) {
      int ca = tid, cb = tid + s;
      float tc[10]; int ti[10]; int pa = 0, pb = 0;
#pragma unroll
      for (int t = 0; t < 10; ++t) {
        float va = lds_c[pa * 256 + ca]; int ia = lds_i[pa * 256 + ca];
        float vb = lds_c[pb * 256 + cb]; int ib = lds_i[pb * 256 + cb];
        bool ta = LESSCI(va, ia, vb, ib) || (va == vb && ia == ib);
        tc[t] = ta ? va : vb; ti[t] = ta ? ia : ib; pa += ta ? 1 : 0; pb += ta ? 0 : 1;
      }
#pragma unroll
      for (int t = 0; t < 10; ++t) { lds_c[t * 256 + ca] = tc[t]; lds_i[t * 256 + ca] = ti[t]; }
    }
    __syncthreads();
  }

  if (dynk <= nV) {   // valid anchors strictly dominate: top-dynk == top-dynk of V
    if (tid == 0) {
      match_n[b * G_N + g] = dynk;
      for (int t = 0; t < dynk; ++t) match_idx[(b * G_N + g) * 10 + t] = lds_i[t * 256];
    }
    return;           // block-uniform
  }

  // ---- fallback (rare): exact full scan with penalties ----
  float c10[10]; int i10[10];
#pragma unroll
  for (int t = 0; t < 10; ++t) { c10[t] = INFINITY; i10[t] = 0x7fffffff; }
  for (int a = tid; a < A_N; a += 256) {
    float cx, cy, st; anchor_info(a, cx, cy, st);
    int cs; const float* pp = chan_base(p0, p1, p2, b, a, cs);
    float px = pp[0], py = pp[cs], pw = pp[2 * cs], ph = pp[3 * cs], obj = pp[4 * cs];
    float iou = pair_iou(gx, gy, gw, gh, px, py, pw, ph);
    float clsv = pp[(5 + cid) * cs];
    float p = sqrtf(clsv * obj);
    float l1 = fmaxf(flog(p), -100.f), l0 = fmaxf(flog(1.f - p), -100.f);
    float cst = (-l1 + l0 - s0[b * A_N + a]) - 3.f * flog(iou + 1e-8f);
    float dx = fabsf(cx - gx), dy = fabsf(cy - gy);
    bool vb2 = (dx < 0.5f * gw) & (dy < 0.5f * gh);
    bool vc2 = (dx < 2.5f * st) & (dy < 2.5f * st);
    if (!(vb2 && vc2)) cst += 100000.f;
    if (!(fgor[b * A_N + a] != 0)) cst += 1e9f;
    if (LESSCI(cst, a, c10[9], i10[9])) {
      float nc = cst; int ni = a;
#pragma unroll
      for (int t = 0; t < 10; ++t) {
        bool lt = LESSCI(nc, ni, c10[t], i10[t]);
        if (lt) { float tf = c10[t]; c10[t] = nc; nc = tf; int ti = i10[t]; i10[t] = ni; ni = ti; }
      }
    }
  }
#pragma unroll
  for (int t = 0; t < 10; ++t) { lds_c[t * 256 + tid] = c10[t]; lds_i[t * 256 + tid] = i10[t]; }
  __syncthreads();
  for (int s = 128; s >= 1; s >>= 1) {
    if (tid < s) {
      int ca = tid, cb = tid + s;
      float tc[10]; int ti[10]; int pa = 0, pb = 0;
#pragma unroll
      for (int t = 0; t < 10; ++t) {
        float va = lds_c[pa * 256 + ca]; int ia = lds_i[pa * 256 + ca];
        float vb = lds_c[pb * 256 + cb]; int ib = lds_i[pb * 256 + cb];
        bool ta = LESSCI(va, ia, vb, ib) || (va == vb && ia == ib);
        tc[t] = ta ? va : vb; ti[t] = ta ? ia : ib; pa += ta ? 1 : 0; pb += ta ? 0 : 1;
      }
#pragma unroll
      for (int t = 0; t < 10; ++t) { lds_c[t * 256 + ca] = tc[t]; lds_i[t * 256 + ca] = ti[t]; }
    }
    __syncthreads();
  }
  if (tid == 0) {
    match_n[b * G_N + g] = dynk;
    for (int t = 0; t < dynk; ++t) match_idx[(b * G_N + g) * 10 + t] = lds_i[t * 256];
  }
}

// ---------- kernel C: dedup & final assignment ----------

__global__ __launch_bounds__(256) void kC(const float* __restrict__ p0, const float* __restrict__ p1,
                                          const float* __restrict__ p2, const float* __restrict__ labels,
                                          const float* __restrict__ s0, const unsigned char* __restrict__ fgor,
                                          const int* __restrict__ match_idx, const int* __restrict__ match_n,
                                          int* __restrict__ asg, float* __restrict__ miou) {
  int b = blockIdx.x, tid = threadIdx.x;
  __shared__ float lab[G_N * 5];
  __shared__ int ent_a[G_N * 10];
  if (tid < G_N * 5) lab[tid] = labels[b * G_N * 5 + tid];
  for (int e = tid; e < G_N * 10; e += 256) {
    int g = e / 10, t = e - g * 10;
    int n = match_n[b * G_N + g];
    ent_a[e] = (t < n) ? match_idx[(b * G_N + g) * 10 + t] : -1;
  }
  __syncthreads();

  for (int e = tid; e < G_N * 10; e += 256) {
    int a = ent_a[e];
    if (a < 0) continue;
    int g = e / 10;
    int cnt = 0;
    for (int e2 = 0; e2 < G_N * 10; ++e2) cnt += (ent_a[e2] == a) ? 1 : 0;

    float cx, cy, st; anchor_info(a, cx, cy, st);
    int cs; const float* pp = chan_base(p0, p1, p2, b, a, cs);
    float px = pp[0], py = pp[cs], pw = pp[2 * cs], ph = pp[3 * cs], obj = pp[4 * cs];

    int gf = g;
    if (cnt > 1) {
      float s0v = s0[b * A_N + a];
      bool fg = fgor[b * A_N + a] != 0;
      float best = INFINITY; gf = 0;
      for (int g2 = 0; g2 < G_N; ++g2) {
        float g2x = lab[g2 * 5 + 1], g2y = lab[g2 * 5 + 2], g2w = lab[g2 * 5 + 3], g2h = lab[g2 * 5 + 4];
        int cid = (int)lab[g2 * 5 + 0];
        float iou = pair_iou(g2x, g2y, g2w, g2h, px, py, pw, ph);
        float clsv = pp[(5 + cid) * cs];
        float p = sqrtf(clsv * obj);
        float l1 = fmaxf(flog(p), -100.f), l0 = fmaxf(flog(1.f - p), -100.f);
        float cst = (-l1 + l0 - s0v) - 3.f * flog(iou + 1e-8f);
        float dx = fabsf(cx - g2x), dy = fabsf(cy - g2y);
        bool vb2 = (dx < 0.5f * g2w) & (dy < 0.5f * g2h);
        bool vc2 = (dx < 2.5f * st) & (dy < 2.5f * st);
        if (!(vb2 && vc2)) cst += 100000.f;
        if (!fg) cst += 1e9f;
        if (cst < best) { best = cst; gf = g2; }
      }
    }
    float gfx = lab[gf * 5 + 1], gfy = lab[gf * 5 + 2], gfw = lab[gf * 5 + 3], gfh = lab[gf * 5 + 4];
    float mi = pair_iou(gfx, gfy, gfw, gfh, px, py, pw, ph);
    asg[b * A_N + a] = gf;
    miou[b * A_N + a] = mi;
  }
}

// ---------- kernel D: per-anchor loss terms + block reduction ----------

__global__ __launch_bounds__(256) void kD(const float* __restrict__ p0, const float* __restrict__ p1,
                                          const float* __restrict__ p2, const float* __restrict__ labels,
                                          const int* __restrict__ asg, const float* __restrict__ miou,
                                          const float* __restrict__ s1,
                                          double* __restrict__ part, int* __restrict__ partn) {
  int b = blockIdx.y, tid = threadIdx.x;
  int a = blockIdx.x * 256 + tid;
  double so = 0.0, si = 0.0, sc = 0.0; int nf = 0;
  if (a < A_N) {
    int cs; const float* pp = chan_base(p0, p1, p2, b, a, cs);
    float obj = pp[4 * cs];
    int g = asg[b * A_N + a];
    if (g >= 0) {
      so = (double)(-fmaxf(flog(obj), -100.f));
      nf = 1;
      float gx = labels[(b * G_N + g) * 5 + 1], gy = labels[(b * G_N + g) * 5 + 2];
      float gw = labels[(b * G_N + g) * 5 + 3], gh = labels[(b * G_N + g) * 5 + 4];
      float px = pp[0], py = pp[cs], pw = pp[2 * cs], ph = pp[3 * cs];
      float iou = pair_iou(gx, gy, gw, gh, px, py, pw, ph);
      si = (double)(1.f - iou * iou);
      float mi = miou[b * A_N + a];
      int cid = (int)labels[(b * G_N + g) * 5 + 0];
      float pc = pp[(5 + cid) * cs];
      float l1c = fmaxf(flog(pc), -100.f);
      float l0c = fmaxf(flog(1.f - pc), -100.f);
      sc = (double)(-s1[b * A_N + a] - mi * l1c + mi * l0c);
    } else {
      so = (double)(-fmaxf(flog(1.f - obj), -100.f));
    }
  }
  __shared__ double ro[256], ri[256], rc[256];
  __shared__ int rn[256];
  ro[tid] = so; ri[tid] = si; rc[tid] = sc; rn[tid] = nf;
  __syncthreads();
  for (int s = 128; s >= 1; s >>= 1) {
    if (tid < s) { ro[tid] += ro[tid + s]; ri[tid] += ri[tid + s]; rc[tid] += rc[tid + s]; rn[tid] += rn[tid + s]; }
    __syncthreads();
  }
  if (tid == 0) {
    int pb = blockIdx.y * gridDim.x + blockIdx.x;
    part[pb * 3 + 0] = ro[0];
    part[pb * 3 + 1] = ri[0];
    part[pb * 3 + 2] = rc[0];
    partn[pb] = rn[0];
  }
}

// ---------- kernel E: final deterministic reduction ----------

__global__ __launch_bounds__(256) void kE(const double* __restrict__ part, const int* __restrict__ partn,
                                          float* __restrict__ out, int nP) {
  int tid = threadIdx.x;
  double o = 0.0, i = 0.0, c = 0.0; int n = 0;
  for (int p = tid; p < nP; p += 256) {
    o += part[p * 3 + 0]; i += part[p * 3 + 1]; c += part[p * 3 + 2]; n += partn[p];
  }
  __shared__ double ro[256], ri[256], rc[256];
  __shared__ int rn[256];
  ro[tid] = o; ri[tid] = i; rc[tid] = c; rn[tid] = n;
  __syncthreads();
  for (int s = 128; s >= 1; s >>= 1) {
    if (tid < s) { ro[tid] += ro[tid + s]; ri[tid] += ri[tid + s]; rc[tid] += rc[tid + s]; rn[tid] += rn[tid + s]; }
    __syncthreads();
  }
  if (tid == 0) {
    float gt = fmaxf((float)rn[0], 1.f);
    float li = (float)((5.0 * ri[0]) / (double)gt);
    float lo = (float)(ro[0] / (double)gt);
    float lc = (float)(rc[0] / (double)gt);
    out[0] = li + lo + lc;
    out[1] = li;
    out[2] = lo;
    out[3] = lc;
    out[4] = gt;
  }
}

// ---------- launch ----------

extern "C" void kernel_launch(void* const* d_in, const int* in_sizes, int n_in,
                              void* d_out, int out_size, void* d_ws, size_t ws_size,
                              hipStream_t stream) {
  const float* p0 = (const float*)d_in[0];
  const float* p1 = (const float*)d_in[1];
  const float* p2 = (const float*)d_in[2];
  const float* labels = (const float*)d_in[3];
  float* out = (float*)d_out;

  char* w = (char*)d_ws;
  auto alloc = [&](size_t bytes) -> void* {
    void* p = (void*)w;
    w += (bytes + 255) & ~(size_t)255;
    return p;
  };
  double* part = (double*)alloc((size_t)NP * 3 * sizeof(double));
  float* s0 = (float*)alloc((size_t)B_N * A_N * sizeof(float));
  float* s1 = (float*)alloc((size_t)B_N * A_N * sizeof(float));
  float* miou = (float*)alloc((size_t)B_N * A_N * sizeof(float));
  int* asg = (int*)alloc((size_t)B_N * A_N * sizeof(int));
  int* match_idx = (int*)alloc((size_t)B_N * G_N * 10 * sizeof(int));
  int* match_n = (int*)alloc((size_t)B_N * G_N * sizeof(int));
  int* partn = (int*)alloc((size_t)NP * sizeof(int));
  unsigned char* fgor = (unsigned char*)alloc((size_t)B_N * A_N);
  float4* F_box = (float4*)alloc((size_t)B_N * A_N * sizeof(float4));
  int* F_cnt = (int*)alloc((size_t)B_N * sizeof(int));

  kZ<<<1, 64, 0, stream>>>(F_cnt);
  dim3 gA(NBLK_A, B_N);
  kA<<<gA, 256, 0, stream>>>(p0, p1, p2, labels, s0, s1, fgor, asg, F_box, F_cnt);
  dim3 gB(G_N, B_N);
  kB<<<gB, 256, 0, stream>>>(p0, p1, p2, labels, s0, fgor, F_box, F_cnt, match_idx, match_n);
  kC<<<B_N, 256, 0, stream>>>(p0, p1, p2, labels, s0, fgor, match_idx, match_n, asg, miou);
  dim3 gD(NBLK_A, B_N);
  kD<<<gD, 256, 0, stream>>>(p0, p1, p2, labels, asg, miou, s1, part, partn);
  kE<<<1, 256, 0, stream>>>(part, partn, out, NP);
}

// Round 4
// 77.457 us; speedup vs baseline: 5.4238x; 1.4875x over previous
//
#include <hip/hip_runtime.h>
#include <cmath>
#include <cfloat>

#define B_N 32
#define A_N 8400
#define G_N 32
#define C_N 80
#define NBLK_A 33            // ceil(8400/256)
#define NP (NBLK_A * B_N)

// ---------- common device helpers ----------

__device__ __forceinline__ float flog(float x) {
  return __log2f(x) * 0.6931471805599453f;
}

// channel base pointer + stride for anchor a (hoists the level branch)
__device__ __forceinline__ const float* chan_base(const float* __restrict__ p0,
                                                  const float* __restrict__ p1,
                                                  const float* __restrict__ p2,
                                                  int b, int a, int& cs) {
  if (a < 6400)      { cs = 6400; return p0 + (size_t)b * 85 * 6400 + a; }
  else if (a < 8000) { cs = 1600; return p1 + (size_t)b * 85 * 1600 + (a - 6400); }
  else               { cs = 400;  return p2 + (size_t)b * 85 * 400  + (a - 8000); }
}

__device__ __forceinline__ void anchor_info(int a, float& cx, float& cy, float& st) {
  if (a < 6400)      { int h = a / 80;            int w = a - h * 80; cx = (w + 0.5f) * 8.f;  cy = (h + 0.5f) * 8.f;  st = 8.f;  }
  else if (a < 8000) { int t = a - 6400; int h = t / 40; int w = t - h * 40; cx = (w + 0.5f) * 16.f; cy = (h + 0.5f) * 16.f; st = 16.f; }
  else               { int t = a - 8000; int h = t / 20; int w = t - h * 20; cx = (w + 0.5f) * 32.f; cy = (h + 0.5f) * 32.f; st = 32.f; }
}

__device__ __forceinline__ float pair_iou(float gx, float gy, float gw, float gh,
                                          float px, float py, float pw, float ph) {
  float gx1 = gx - 0.5f * gw, gy1 = gy - 0.5f * gh, gx2 = gx + 0.5f * gw, gy2 = gy + 0.5f * gh;
  float px1 = px - 0.5f * pw, py1 = py - 0.5f * ph, px2 = px + 0.5f * pw, py2 = py + 0.5f * ph;
  float iw = fmaxf(fminf(gx2, px2) - fmaxf(gx1, px1), 0.f);
  float ih = fmaxf(fminf(gy2, py2) - fmaxf(gy1, py1), 0.f);
  float inter = iw * ih;
  return inter / (gw * gh + pw * ph - inter + 1e-16f);
}

// ---------- kernel Z: zero fg counters ----------

__global__ void kZ(int* __restrict__ F_cnt) {
  if (threadIdx.x < B_N) F_cnt[threadIdx.x] = 0;
}

// ---------- kernel A: s0/s1, fg_or, asg init, fg-box compaction ----------

__global__ __launch_bounds__(256) void kA(const float* __restrict__ p0, const float* __restrict__ p1,
                                          const float* __restrict__ p2, const float* __restrict__ labels,
                                          float* __restrict__ s0, float* __restrict__ s1,
                                          unsigned char* __restrict__ fgor,
                                          int* __restrict__ asg,
                                          float4* __restrict__ F_box, int* __restrict__ F_cnt) {
  int b = blockIdx.y, tid = threadIdx.x;
  int a = blockIdx.x * 256 + tid;
  __shared__ float4 labf[G_N];          // (gx, gy, 0.5*gw, 0.5*gh)
  __shared__ float4 stage[256];
  __shared__ int s_cnt, s_base;
  if (tid < G_N) {
    const float* L = labels + (size_t)(b * G_N + tid) * 5;
    labf[tid] = make_float4(L[1], L[2], 0.5f * L[3], 0.5f * L[4]);
  }
  if (tid == 0) s_cnt = 0;
  __syncthreads();

  bool active = (a < A_N);
  bool fg = false;
  const float* pp = nullptr; int cs = 0;
  if (active) {
    pp = chan_base(p0, p1, p2, b, a, cs);
    float obj = pp[4 * cs];
    float l2s = 0.f, l2r = 0.f;
    for (int c = 0; c < C_N; c += 4) {
      float v0 = pp[(5 + c) * cs], v1 = pp[(6 + c) * cs], v2 = pp[(7 + c) * cs], v3 = pp[(8 + c) * cs];
      float q0 = 1.f - sqrtf(v0 * obj), q1 = 1.f - sqrtf(v1 * obj);
      float q2 = 1.f - sqrtf(v2 * obj), q3 = 1.f - sqrtf(v3 * obj);
      float r0 = 1.f - v0, r1 = 1.f - v1, r2 = 1.f - v2, r3 = 1.f - v3;
      l2s += __log2f(fmaxf((q0 * q1) * (q2 * q3), 1e-37f));
      l2r += __log2f(fmaxf((r0 * r1) * (r2 * r3), 1e-37f));
    }
    s0[b * A_N + a] = l2s * 0.6931471805599453f;
    s1[b * A_N + a] = l2r * 0.6931471805599453f;

    float cx, cy, st; anchor_info(a, cx, cy, st);
    float rr = 2.5f * st;
    for (int g = 0; g < G_N; ++g) {
      float4 L = labf[g];
      float dx = fabsf(cx - L.x), dy = fabsf(cy - L.y);
      fg = fg | ((dx < L.z) & (dy < L.w)) | ((dx < rr) & (dy < rr));
    }
    fgor[b * A_N + a] = fg ? 1 : 0;
    asg[b * A_N + a] = -1;
  }
  if (active && fg) {
    int pos = atomicAdd(&s_cnt, 1);
    stage[pos] = make_float4(pp[0], pp[cs], pp[2 * cs], pp[3 * cs]);
  }
  __syncthreads();
  if (tid == 0) s_base = atomicAdd(&F_cnt[b], s_cnt);
  __syncthreads();
  for (int i = tid; i < s_cnt; i += 256)
    F_box[(size_t)b * A_N + s_base + i] = stage[i];
}

// ---------- kernel B: per-(b,g) dyn_k + top-k selection; dense -1-padded output ----------

#define LESSCI(c1, i1, c2, i2) (((c1) < (c2)) || ((c1) == (c2) && (i1) < (i2)))

__global__ __launch_bounds__(256) void kB(const float* __restrict__ p0, const float* __restrict__ p1,
                                          const float* __restrict__ p2, const float* __restrict__ labels,
                                          const float* __restrict__ s0, const unsigned char* __restrict__ fgor,
                                          const float4* __restrict__ F_box, const int* __restrict__ F_cnt,
                                          int* __restrict__ match_idx) {
  int g = blockIdx.x, b = blockIdx.y, tid = threadIdx.x;
  __shared__ float lds_c[10 * 256];
  __shared__ int   lds_i[10 * 256];
  __shared__ float slab[5];
  __shared__ int s_nV, s_dynk;
  if (tid < 5) slab[tid] = labels[(b * G_N + g) * 5 + tid];
  if (tid == 0) s_nV = 0;
  __syncthreads();
  float gx = slab[1], gy = slab[2], gw = slab[3], gh = slab[4];
  int cid = (int)slab[0];

  // ---- phase A: top-10 iou VALUES over compacted fg boxes (order-independent) ----
  float v10[10];
#pragma unroll
  for (int t = 0; t < 10; ++t) v10[t] = 0.f;
  int nF = F_cnt[b];
  const float4* bx = F_box + (size_t)b * A_N;
  for (int i = tid; i < nF; i += 256) {
    float4 B = bx[i];
    float iou = pair_iou(gx, gy, gw, gh, B.x, B.y, B.z, B.w);
    if (iou > v10[9]) {
      float nv = iou;
#pragma unroll
      for (int t = 0; t < 10; ++t)
        if (nv > v10[t]) { float tf = v10[t]; v10[t] = nv; nv = tf; }
    }
  }
#pragma unroll
  for (int t = 0; t < 10; ++t) lds_c[t * 256 + tid] = v10[t];
  __syncthreads();
  for (int s = 128; s >= 1; s >>= 1) {
    if (tid < s) {
      int ca = tid, cb = tid + s;
      float tv[10]; int qa = 0, qb = 0;
#pragma unroll
      for (int t = 0; t < 10; ++t) {
        float va = lds_c[qa * 256 + ca], vb = lds_c[qb * 256 + cb];
        bool ta = va >= vb;
        tv[t] = ta ? va : vb; qa += ta ? 1 : 0; qb += ta ? 0 : 1;
      }
#pragma unroll
      for (int t = 0; t < 10; ++t) lds_c[t * 256 + ca] = tv[t];
    }
    __syncthreads();
  }
  if (tid == 0) {
    float sum = 0.f;
#pragma unroll
    for (int t = 0; t < 10; ++t) sum += lds_c[t * 256];
    int k = (int)sum; if (k < 1) k = 1; if (k > 10) k = 10;
    s_dynk = k;
  }
  __syncthreads();
  int dynk = s_dynk;

  // ---- phase B: geometric valid candidates (<=147), exact cost, no penalties ----
  float cc = INFINITY; int ci = 0x7fffffff;
  if (tid < 147) {
    int lvl = tid / 49, r2 = tid % 49;
    int dh = r2 / 7 - 3, dw = r2 % 7 - 3;
    float st = (lvl == 0) ? 8.f : (lvl == 1) ? 16.f : 32.f;
    int Wg = (lvl == 0) ? 80 : (lvl == 1) ? 40 : 20;
    int basea = (lvl == 0) ? 0 : (lvl == 1) ? 6400 : 8000;
    int hc = (int)floorf(gy / st) + dh, wc = (int)floorf(gx / st) + dw;
    if (hc >= 0 && hc < Wg && wc >= 0 && wc < Wg) {
      int a = basea + hc * Wg + wc;
      float cx = (wc + 0.5f) * st, cy = (hc + 0.5f) * st;
      float dx = fabsf(cx - gx), dy = fabsf(cy - gy);
      bool ic = (dx < 2.5f * st) & (dy < 2.5f * st);
      bool ib = (dx < 0.5f * gw) & (dy < 0.5f * gh);
      if (ic && ib) {
        atomicAdd(&s_nV, 1);
        int cs; const float* pp = chan_base(p0, p1, p2, b, a, cs);
        float px = pp[0], py = pp[cs], pw = pp[2 * cs], ph = pp[3 * cs], obj = pp[4 * cs];
        float clsv = pp[(5 + cid) * cs];
        float iou = pair_iou(gx, gy, gw, gh, px, py, pw, ph);
        float p = sqrtf(clsv * obj);
        float l1 = fmaxf(flog(p), -100.f), l0 = fmaxf(flog(1.f - p), -100.f);
        cc = (-l1 + l0 - s0[b * A_N + a]) - 3.f * flog(iou + 1e-8f);
        ci = a;
      }
    }
  }
  lds_c[tid] = cc; lds_i[tid] = ci;
#pragma unroll
  for (int t = 1; t < 10; ++t) { lds_c[t * 256 + tid] = INFINITY; lds_i[t * 256 + tid] = 0x7fffffff; }
  __syncthreads();
  int nV = s_nV;
  for (int s = 128; s >= 1; s >>= 1) {
    if (tid < s) {
      int ca = tid, cb = tid + s;
      float tc[10]; int ti[10]; int pa = 0, pb = 0;
#pragma unroll
      for (int t = 0; t < 10; ++t) {
        float va = lds_c[pa * 256 + ca]; int ia = lds_i[pa * 256 + ca];
        float vb = lds_c[pb * 256 + cb]; int ib = lds_i[pb * 256 + cb];
        bool ta = LESSCI(va, ia, vb, ib) || (va == vb && ia == ib);
        tc[t] = ta ? va : vb; ti[t] = ta ? ia : ib; pa += ta ? 1 : 0; pb += ta ? 0 : 1;
      }
#pragma unroll
      for (int t = 0; t < 10; ++t) { lds_c[t * 256 + ca] = tc[t]; lds_i[t * 256 + ca] = ti[t]; }
    }
    __syncthreads();
  }

  if (dynk <= nV) {   // valid anchors strictly dominate: top-dynk == top-dynk of V
    if (tid == 0) {
      for (int t = 0; t < 10; ++t)
        match_idx[(b * G_N + g) * 10 + t] = (t < dynk) ? lds_i[t * 256] : -1;
    }
    return;           // block-uniform
  }

  // ---- fallback (rare): exact full scan with penalties ----
  float c10[10]; int i10[10];
#pragma unroll
  for (int t = 0; t < 10; ++t) { c10[t] = INFINITY; i10[t] = 0x7fffffff; }
  for (int a = tid; a < A_N; a += 256) {
    float cx, cy, st; anchor_info(a, cx, cy, st);
    int cs; const float* pp = chan_base(p0, p1, p2, b, a, cs);
    float px = pp[0], py = pp[cs], pw = pp[2 * cs], ph = pp[3 * cs], obj = pp[4 * cs];
    float iou = pair_iou(gx, gy, gw, gh, px, py, pw, ph);
    float clsv = pp[(5 + cid) * cs];
    float p = sqrtf(clsv * obj);
    float l1 = fmaxf(flog(p), -100.f), l0 = fmaxf(flog(1.f - p), -100.f);
    float cst = (-l1 + l0 - s0[b * A_N + a]) - 3.f * flog(iou + 1e-8f);
    float dx = fabsf(cx - gx), dy = fabsf(cy - gy);
    bool vb2 = (dx < 0.5f * gw) & (dy < 0.5f * gh);
    bool vc2 = (dx < 2.5f * st) & (dy < 2.5f * st);
    if (!(vb2 && vc2)) cst += 100000.f;
    if (!(fgor[b * A_N + a] != 0)) cst += 1e9f;
    if (LESSCI(cst, a, c10[9], i10[9])) {
      float nc = cst; int ni = a;
#pragma unroll
      for (int t = 0; t < 10; ++t) {
        bool lt = LESSCI(nc, ni, c10[t], i10[t]);
        if (lt) { float tf = c10[t]; c10[t] = nc; nc = tf; int ti = i10[t]; i10[t] = ni; ni = ti; }
      }
    }
  }
#pragma unroll
  for (int t = 0; t < 10; ++t) { lds_c[t * 256 + tid] = c10[t]; lds_i[t * 256 + tid] = i10[t]; }
  __syncthreads();
  for (int s = 128; s >= 1; s >>= 1) {
    if (tid < s) {
      int ca = tid, cb = tid + s;
      float tc[10]; int ti[10]; int pa = 0, pb = 0;
#pragma unroll
      for (int t = 0; t < 10; ++t) {
        float va = lds_c[pa * 256 + ca]; int ia = lds_i[pa * 256 + ca];
        float vb = lds_c[pb * 256 + cb]; int ib = lds_i[pb * 256 + cb];
        bool ta = LESSCI(va, ia, vb, ib) || (va == vb && ia == ib);
        tc[t] = ta ? va : vb; ti[t] = ta ? ia : ib; pa += ta ? 1 : 0; pb += ta ? 0 : 1;
      }
#pragma unroll
      for (int t = 0; t < 10; ++t) { lds_c[t * 256 + ca] = tc[t]; lds_i[t * 256 + ca] = ti[t]; }
    }
    __syncthreads();
  }
  if (tid == 0) {
    for (int t = 0; t < 10; ++t)
      match_idx[(b * G_N + g) * 10 + t] = (t < dynk) ? lds_i[t * 256] : -1;
  }
}

// ---------- kernel C1: one wavefront per match entry — dedup + argmin ----------
// Note: s0 and the fg penalty are per-anchor (column-uniform) -> cannot change
// the argmin over gts -> omitted here.

__global__ __launch_bounds__(64) void kC1(const float* __restrict__ p0, const float* __restrict__ p1,
                                          const float* __restrict__ p2, const float* __restrict__ labels,
                                          const int* __restrict__ match_idx,
                                          int* __restrict__ asg, float* __restrict__ miou) {
  int e = blockIdx.x, b = blockIdx.y, lane = threadIdx.x;
  const int* ent = match_idx + (size_t)b * G_N * 10;
  int a = ent[e];
  if (a < 0) return;                       // block-uniform

  // cnt = number of entries (== gts) claiming anchor a
  int cnt = 0;
#pragma unroll
  for (int k = 0; k < 5; ++k) {
    int v = ent[lane + 64 * k];
    unsigned long long m = __ballot(v == a);
    cnt += __popcll(m);
  }

  int cs; const float* pp = chan_base(p0, p1, p2, b, a, cs);
  float px = pp[0], py = pp[cs], pw = pp[2 * cs], ph = pp[3 * cs];

  int gf = e / 10;
  if (cnt > 1) {
    float obj = pp[4 * cs];
    float cx, cy, st; anchor_info(a, cx, cy, st);
    float cost = INFINITY; int idx = 0x7fffffff;
    if (lane < G_N) {
      const float* L = labels + (size_t)(b * G_N + lane) * 5;
      int cid = (int)L[0];
      float g2x = L[1], g2y = L[2], g2w = L[3], g2h = L[4];
      float iou = pair_iou(g2x, g2y, g2w, g2h, px, py, pw, ph);
      float clsv = pp[(5 + cid) * cs];
      float p = sqrtf(clsv * obj);
      float l1 = fmaxf(flog(p), -100.f), l0 = fmaxf(flog(1.f - p), -100.f);
      cost = (-l1 + l0) - 3.f * flog(iou + 1e-8f);
      float dx = fabsf(cx - g2x), dy = fabsf(cy - g2y);
      bool vb2 = (dx < 0.5f * g2w) & (dy < 0.5f * g2h);
      bool vc2 = (dx < 2.5f * st) & (dy < 2.5f * st);
      if (!(vb2 && vc2)) cost += 100000.f;
      idx = lane;
    }
    // wave argmin with first-index tiebreak
#pragma unroll
    for (int off = 32; off >= 1; off >>= 1) {
      float oc = __shfl_xor(cost, off);
      int oi = __shfl_xor(idx, off);
      if (LESSCI(oc, oi, cost, idx)) { cost = oc; idx = oi; }
    }
    gf = idx;
  }

  if (lane == 0) {
    const float* L = labels + (size_t)(b * G_N + gf) * 5;
    float mi = pair_iou(L[1], L[2], L[3], L[4], px, py, pw, ph);
    asg[b * A_N + a] = gf;                 // duplicate writers write identical values
    miou[b * A_N + a] = mi;
  }
}

// ---------- kernel D: per-anchor loss terms + block reduction ----------

__global__ __launch_bounds__(256) void kD(const float* __restrict__ p0, const float* __restrict__ p1,
                                          const float* __restrict__ p2, const float* __restrict__ labels,
                                          const int* __restrict__ asg, const float* __restrict__ miou,
                                          const float* __restrict__ s1,
                                          double* __restrict__ part, int* __restrict__ partn) {
  int b = blockIdx.y, tid = threadIdx.x;
  int a = blockIdx.x * 256 + tid;
  double so = 0.0, si = 0.0, sc = 0.0; int nf = 0;
  if (a < A_N) {
    int cs; const float* pp = chan_base(p0, p1, p2, b, a, cs);
    float obj = pp[4 * cs];
    int g = asg[b * A_N + a];
    if (g >= 0) {
      so = (double)(-fmaxf(flog(obj), -100.f));
      nf = 1;
      float gx = labels[(b * G_N + g) * 5 + 1], gy = labels[(b * G_N + g) * 5 + 2];
      float gw = labels[(b * G_N + g) * 5 + 3], gh = labels[(b * G_N + g) * 5 + 4];
      float px = pp[0], py = pp[cs], pw = pp[2 * cs], ph = pp[3 * cs];
      float iou = pair_iou(gx, gy, gw, gh, px, py, pw, ph);
      si = (double)(1.f - iou * iou);
      float mi = miou[b * A_N + a];
      int cid = (int)labels[(b * G_N + g) * 5 + 0];
      float pc = pp[(5 + cid) * cs];
      float l1c = fmaxf(flog(pc), -100.f);
      float l0c = fmaxf(flog(1.f - pc), -100.f);
      sc = (double)(-s1[b * A_N + a] - mi * l1c + mi * l0c);
    } else {
      so = (double)(-fmaxf(flog(1.f - obj), -100.f));
    }
  }
  __shared__ double ro[256], ri[256], rc[256];
  __shared__ int rn[256];
  ro[tid] = so; ri[tid] = si; rc[tid] = sc; rn[tid] = nf;
  __syncthreads();
  for (int s = 128; s >= 1; s >>= 1) {
    if (tid < s) { ro[tid] += ro[tid + s]; ri[tid] += ri[tid + s]; rc[tid] += rc[tid + s]; rn[tid] += rn[tid + s]; }
    __syncthreads();
  }
  if (tid == 0) {
    int pb = blockIdx.y * gridDim.x + blockIdx.x;
    part[pb * 3 + 0] = ro[0];
    part[pb * 3 + 1] = ri[0];
    part[pb * 3 + 2] = rc[0];
    partn[pb] = rn[0];
  }
}

// ---------- kernel E: final deterministic reduction ----------

__global__ __launch_bounds__(256) void kE(const double* __restrict__ part, const int* __restrict__ partn,
                                          float* __restrict__ out, int nP) {
  int tid = threadIdx.x;
  double o = 0.0, i = 0.0, c = 0.0; int n = 0;
  for (int p = tid; p < nP; p += 256) {
    o += part[p * 3 + 0]; i += part[p * 3 + 1]; c += part[p * 3 + 2]; n += partn[p];
  }
  __shared__ double ro[256], ri[256], rc[256];
  __shared__ int rn[256];
  ro[tid] = o; ri[tid] = i; rc[tid] = c; rn[tid] = n;
  __syncthreads();
  for (int s = 128; s >= 1; s >>= 1) {
    if (tid < s) { ro[tid] += ro[tid + s]; ri[tid] += ri[tid + s]; rc[tid] += rc[tid + s]; rn[tid] += rn[tid + s]; }
    __syncthreads();
  }
  if (tid == 0) {
    float gt = fmaxf((float)rn[0], 1.f);
    float li = (float)((5.0 * ri[0]) / (double)gt);
    float lo = (float)(ro[0] / (double)gt);
    float lc = (float)(rc[0] / (double)gt);
    out[0] = li + lo + lc;
    out[1] = li;
    out[2] = lo;
    out[3] = lc;
    out[4] = gt;
  }
}

// ---------- launch ----------

extern "C" void kernel_launch(void* const* d_in, const int* in_sizes, int n_in,
                              void* d_out, int out_size, void* d_ws, size_t ws_size,
                              hipStream_t stream) {
  const float* p0 = (const float*)d_in[0];
  const float* p1 = (const float*)d_in[1];
  const float* p2 = (const float*)d_in[2];
  const float* labels = (const float*)d_in[3];
  float* out = (float*)d_out;

  char* w = (char*)d_ws;
  auto alloc = [&](size_t bytes) -> void* {
    void* p = (void*)w;
    w += (bytes + 255) & ~(size_t)255;
    return p;
  };
  double* part = (double*)alloc((size_t)NP * 3 * sizeof(double));
  float* s0 = (float*)alloc((size_t)B_N * A_N * sizeof(float));
  float* s1 = (float*)alloc((size_t)B_N * A_N * sizeof(float));
  float* miou = (float*)alloc((size_t)B_N * A_N * sizeof(float));
  int* asg = (int*)alloc((size_t)B_N * A_N * sizeof(int));
  int* match_idx = (int*)alloc((size_t)B_N * G_N * 10 * sizeof(int));
  int* partn = (int*)alloc((size_t)NP * sizeof(int));
  unsigned char* fgor = (unsigned char*)alloc((size_t)B_N * A_N);
  float4* F_box = (float4*)alloc((size_t)B_N * A_N * sizeof(float4));
  int* F_cnt = (int*)alloc((size_t)B_N * sizeof(int));

  kZ<<<1, 64, 0, stream>>>(F_cnt);
  dim3 gA(NBLK_A, B_N);
  kA<<<gA, 256, 0, stream>>>(p0, p1, p2, labels, s0, s1, fgor, asg, F_box, F_cnt);
  dim3 gB(G_N, B_N);
  kB<<<gB, 256, 0, stream>>>(p0, p1, p2, labels, s0, fgor, F_box, F_cnt, match_idx);
  dim3 gC(G_N * 10, B_N);
  kC1<<<gC, 64, 0, stream>>>(p0, p1, p2, labels, match_idx, asg, miou);
  dim3 gD(NBLK_A, B_N);
  kD<<<gD, 256, 0, stream>>>(p0, p1, p2, labels, asg, miou, s1, part, partn);
  kE<<<1, 256, 0, stream>>>(part, partn, out, NP);
}